// Round 13
// baseline (646.236 us; speedup 1.0000x reference)
//
#include <hip/hip_runtime.h>
#include <math.h>

#define NPTS  16384
#define KNN   16
#define SEQV  8
#define NPART 16
#define SLICE 1024    // candidates per block (partition)
#define CHUNK 256     // LDS staging chunk (4 KB), double-buffered
#define BATCH 8
#define CAP   25      // append buf words/thread; odd stride -> conflict-free

__device__ __forceinline__ unsigned umin_(unsigned a, unsigned b) { return a < b ? a : b; }
__device__ __forceinline__ unsigned umax_(unsigned a, unsigned b) { return a > b ? a : b; }

// merge one key into sorted ascending keys[16]
__device__ __forceinline__ void merge_one(unsigned keys[KNN], unsigned kk) {
    if (kk < keys[KNN - 1]) {
#pragma unroll
        for (int u = 0; u < KNN; ++u) {
            unsigned lo = umin_(kk, keys[u]);
            kk = umax_(kk, keys[u]);
            keys[u] = lo;
        }
    }
}

// ---------------------------------------------------------------------------
// K1: self-bootstrapping filtered kNN scan. Grid (64, NPART) x 256.
// Block (bx,p): queries [256bx, 256bx+256) vs slice [1024p, 1024p+1024).
// Slice is staged into LDS in 4 double-buffered 4 KB chunks (coalesced
// global loads + ds_write_b128); the scan reads candidates via broadcast
// ds_read_b128 (in-order -> partial lgkmcnt waits, unlike SMEM's full
// drain that capped R9 at 88 us). tau starts +inf; the flush-tighten
// machinery bootstraps it (first flush: cnt>=17 -> tau = margined 16th of
// seen -> exact). Lists written transposed: part[i][p][16].
// key = (d2 bits & 0xFFFFC000) | j  (j < 2^14).
// ---------------------------------------------------------------------------
__global__ __launch_bounds__(256, 4) void knn_kernel(
    const float* __restrict__ pc, unsigned* __restrict__ part,
    float* __restrict__ accum)
{
    __shared__ float4   sStage[2 * CHUNK];   // 8 KB, double-buffered
    __shared__ unsigned sbuf[256 * CAP];     // 25.6 KB append buffers
    unsigned* buf = &sbuf[threadIdx.x * CAP];

    const int tid = threadIdx.x;
    const int i   = blockIdx.x * 256 + tid;
    const int p   = blockIdx.y;

    if (blockIdx.x == 0 && p == 0 && tid == 0) {
        accum[0] = 0.0f; accum[1] = 0.0f;
        ((unsigned*)accum)[2] = 0u; ((unsigned*)accum)[3] = 0u;
    }

    const float qx = pc[3 * i + 0];
    const float qy = pc[3 * i + 1];
    const float qz = pc[3 * i + 2];
    const float q2 = fmaf(qx, qx, fmaf(qy, qy, qz * qz));

    unsigned keys[KNN];
#pragma unroll
    for (int t = 0; t < KNN; ++t) keys[t] = 0xFFFFFFFFu;
    float tauf = INFINITY;
    int cnt = 0;

    const int jbeg = p * SLICE;

    // ---- stage chunk 0 ----
    {
        const int j = jbeg + tid;
        float x = pc[3 * j + 0], y = pc[3 * j + 1], z = pc[3 * j + 2];
        sStage[tid] = make_float4(x, y, z, fmaf(x, x, fmaf(y, y, z * z)));
    }
    __syncthreads();

    auto process = [&](const float4* C, int jbase) {
#pragma unroll
        for (int q = 0; q < BATCH; ++q) {
            const float4 c = C[q];
            float dot = fmaf(c.x, qx, fmaf(c.y, qy, c.z * qz));
            float d2p = fmaf(-2.0f, dot, c.w);     // d2 - |q|^2 (monotone)
            if (d2p <= tauf) {                     // exec-masked accept
                float d2 = fmaxf(d2p + q2, 0.0f);  // clamp: self ~ -1e-7
                buf[cnt] = (__float_as_uint(d2) & 0xFFFFC000u)
                         | (unsigned)(jbeg + jbase + q);
                ++cnt;
            }
        }
        // headroom: enter batch with cnt <= 16 -> max idx 24 = CAP-1
        if (cnt >= CAP - BATCH) {
#pragma unroll 1
            for (int t = 0; t < cnt; ++t) merge_one(keys, buf[t]);
            cnt = 0;
            float d16 = __uint_as_float(keys[KNN - 1] & 0xFFFFC000u);
            // margin covers fma/truncation rounding; fminf is NaN-safe
            tauf = fminf(tauf, fmaf(d16, 1.0002f, 1e-6f) - q2);
        }
    };

#pragma unroll 1
    for (int c = 0; c < SLICE / CHUNK; ++c) {
        // issue next chunk's global loads before processing this one
        float nx, ny, nz;
        const bool more = (c + 1 < SLICE / CHUNK);
        if (more) {
            const int j = jbeg + (c + 1) * CHUNK + tid;
            nx = pc[3 * j + 0]; ny = pc[3 * j + 1]; nz = pc[3 * j + 2];
        }

        // process chunk c from LDS, register ping-pong
        const float4* sc = &sStage[(c & 1) * CHUNK];
        float4 A[BATCH], B[BATCH];
#pragma unroll
        for (int q = 0; q < BATCH; ++q) A[q] = sc[q];

#pragma unroll 1
        for (int jo = 0; jo < CHUNK; jo += 2 * BATCH) {
#pragma unroll
            for (int q = 0; q < BATCH; ++q) B[q] = sc[jo + BATCH + q];
            process(A, c * CHUNK + jo);
            if (jo + 2 * BATCH < CHUNK) {
#pragma unroll
                for (int q = 0; q < BATCH; ++q) A[q] = sc[jo + 2 * BATCH + q];
            }
            process(B, c * CHUNK + jo + BATCH);
        }

        if (more) {
            sStage[((c + 1) & 1) * CHUNK + tid] =
                make_float4(nx, ny, nz, fmaf(nx, nx, fmaf(ny, ny, nz * nz)));
        }
        __syncthreads();
    }

#pragma unroll 1
    for (int t = 0; t < cnt; ++t) merge_one(keys, buf[t]);

    unsigned* dst = part + ((size_t)i * NPART + p) * KNN;
#pragma unroll
    for (int t = 0; t < KNN; ++t) dst[t] = keys[t];
}

// ---------------------------------------------------------------------------
// K2: merge + radius + loss + wsum + finalize. Grid (64,4) x 512.
// Split-merge (R9-proven): e==0 merges lists 0..7, e==1 merges 8..15
// (ping-pong prefetched), halves meet in LDS, e==0 cross-merges + radius
// -> ids in LDS. All threads gather seq s = 2*sg + e. sg==0/e==0 waves
// also accumulate the weight sum.
// accum[0]=loss, accum[1]=wsum, accum[2]=ticket (zeroed by knn_kernel).
// ---------------------------------------------------------------------------
__global__ __launch_bounds__(512) void loss_kernel(
    const float* __restrict__ flow, const float* __restrict__ w,
    const unsigned* __restrict__ part, float* __restrict__ accum,
    float* __restrict__ out)
{
    __shared__ unsigned sKeys[256 * 34];   // q*34 + e*17 + t
    __shared__ float sred[8];

    const int tid = threadIdx.x;
    const int q   = tid & 255;
    const int e   = tid >> 8;          // 0..1
    const int i   = blockIdx.x * 256 + q;
    const int sg  = blockIdx.y;        // 0..3

    const uint4* lists = (const uint4*)(part + ((size_t)i * NPART + e * 8) * KNN);

    unsigned keys[KNN];
#pragma unroll
    for (int t = 0; t < KNN; ++t) keys[t] = 0xFFFFFFFFu;

    uint4 A4[4], B4[4];
#pragma unroll
    for (int u = 0; u < 4; ++u) A4[u] = lists[u];

    auto merge_list = [&](const uint4* L) {
        const unsigned* lk = (const unsigned*)L;
#pragma unroll
        for (int t = 0; t < KNN; ++t) merge_one(keys, lk[t]);
    };

#pragma unroll 1
    for (int p = 0; p < 8; p += 2) {
#pragma unroll
        for (int u = 0; u < 4; ++u) B4[u] = lists[4 * (p + 1) + u];
        merge_list(A4);
        if (p + 2 < 8) {
#pragma unroll
            for (int u = 0; u < 4; ++u) A4[u] = lists[4 * (p + 2) + u];
        }
        merge_list(B4);
    }

#pragma unroll
    for (int t = 0; t < KNN; ++t) sKeys[q * 34 + e * 17 + t] = keys[t];
    __syncthreads();

    if (e == 0) {
#pragma unroll
        for (int t = 0; t < KNN; ++t) merge_one(keys, sKeys[q * 34 + 17 + t]);
        const int id0 = (int)(keys[0] & 0x3FFFu);   // nearest (self)
#pragma unroll
        for (int t = 0; t < KNN; ++t) {
            float d2t = __uint_as_float(keys[t] & 0xFFFFC000u);
            int   j   = (int)(keys[t] & 0x3FFFu);
            sKeys[q * 34 + t] = (unsigned)((d2t > 1.0f) ? id0 : j);
        }
        if (sg == 0) {                  // weight sum exactly once
            float wi = w[i];
#pragma unroll
            for (int off = 32; off > 0; off >>= 1) wi += __shfl_down(wi, off);
            if ((tid & 63) == 0) atomicAdd(&accum[1], wi);
        }
    }
    __syncthreads();

    const int s = sg * 2 + e;
    const float* fs = flow + (size_t)s * NPTS * 3;
    const float fx = fs[3 * i + 0];
    const float fy = fs[3 * i + 1];
    const float fz = fs[3 * i + 2];

    float sum = 0.0f;
#pragma unroll
    for (int t = 0; t < KNN; ++t) {
        int j = (int)sKeys[q * 34 + t];
        float dx = fx - fs[3 * j + 0];
        float dy = fy - fs[3 * j + 1];
        float dz = fz - fs[3 * j + 2];
        float sq = fmaf(dx, dx, fmaf(dy, dy, dz * dz));
        sum += (sq > 0.0f) ? sqrtf(sq) : 0.0f;
    }

    float contrib = w[i] * sum;
#pragma unroll
    for (int off = 32; off > 0; off >>= 1) contrib += __shfl_down(contrib, off);
    if ((tid & 63) == 0) sred[tid >> 6] = contrib;
    __syncthreads();

    if (tid == 0) {
        float c = 0.0f;
#pragma unroll
        for (int t = 0; t < 8; ++t) c += sred[t];
        atomicAdd(&accum[0], c);
        __threadfence();
        unsigned ticket = atomicAdd((unsigned*)&accum[2], 1u);
        if (ticket == 64 * 4 - 1) {     // last block finalizes
            float a  = atomicAdd(&accum[0], 0.0f);   // coherent read
            float ws = atomicAdd(&accum[1], 0.0f);
            float v  = a / (float)(KNN * SEQV);
            out[0] = (ws > 0.0f) ? (v / ws) : v;
        }
    }
}

extern "C" void kernel_launch(void* const* d_in, const int* in_sizes, int n_in,
                              void* d_out, int out_size, void* d_ws, size_t ws_size,
                              hipStream_t stream)
{
    const float* pc   = (const float*)d_in[0];   // (1, N, 3)
    const float* flow = (const float*)d_in[1];   // (SEQ, N, 3)
    const float* wts  = (const float*)d_in[2];   // (N,)
    float* out = (float*)d_out;

    // layout: accum(256 B) | part (16.8 MB, transposed part[i][p][16])
    float*    accum = (float*)d_ws;
    unsigned* part  = (unsigned*)((char*)d_ws + 256);

    knn_kernel<<<dim3(NPTS / 256, NPART), 256, 0, stream>>>(pc, part, accum);
    loss_kernel<<<dim3(NPTS / 256, 4), 512, 0, stream>>>(flow, wts, part, accum, out);
}

// Round 14
// 225.211 us; speedup vs baseline: 2.8695x; 2.8695x over previous
//
#include <hip/hip_runtime.h>
#include <math.h>

#define NPTS  16384
#define KNN   16
#define SEQV  8
#define NPART 16
#define PLEN  (NPTS / NPART)   // 1024
#define SEGS  8                // sample segments (one per wave of K1)
#define RUN   256              // candidates sampled per segment (total 2048)
#define BATCH 8
#define CAP   25               // odd stride -> spread banks; 25.6 KB/block

__device__ __forceinline__ unsigned umin_(unsigned a, unsigned b) { return a < b ? a : b; }
__device__ __forceinline__ unsigned umax_(unsigned a, unsigned b) { return a > b ? a : b; }

// merge one key into sorted ascending keys[16]
__device__ __forceinline__ void merge_one(unsigned keys[KNN], unsigned kk) {
    if (kk < keys[KNN - 1]) {
#pragma unroll
        for (int u = 0; u < KNN; ++u) {
            unsigned lo = umin_(kk, keys[u]);
            kk = umax_(kk, keys[u]);
            keys[u] = lo;
        }
    }
}

// ---------------------------------------------------------------------------
// K1: fused sample+tau. Grid 256 x 512 (8 waves/block, 2 waves/SIMD).
// Wave wv handles all 64 of the block's queries (lane = query) against the
// first RUN candidates of chunk [2048*wv, 2048*wv+RUN): cold chain with
// ping-pong s_load prefetch (seg index laundered via readfirstlane to keep
// the scalar path). 3-round LDS tree merge -> tau over the 2048-sample
// (>= global 16th => exact filter bound). wv==0 also writes pc4[i] =
// (x,y,z,|c|^2); block 0 zeroes accum. No global list traffic at all.
// key = (d2 bits & 0xFFFFC000) | j  (j < 2^14).
// ---------------------------------------------------------------------------
__global__ __launch_bounds__(512) void sample_tau_kernel(
    const float* __restrict__ pc, float4* __restrict__ pc4,
    float* __restrict__ taufArr, float* __restrict__ accum)
{
    __shared__ unsigned sK[512 * 17];    // 34.8 KB, stride 17 conflict-free

    const int tid  = threadIdx.x;
    const int lane = tid & 63;
    const int wv   = __builtin_amdgcn_readfirstlane(tid >> 6);   // 0..7
    const int i    = blockIdx.x * 64 + lane;

    if (blockIdx.x == 0 && tid == 0) {
        accum[0] = 0.0f; accum[1] = 0.0f;
        ((unsigned*)accum)[2] = 0u; ((unsigned*)accum)[3] = 0u;
    }

    const float qx = pc[3 * i + 0];
    const float qy = pc[3 * i + 1];
    const float qz = pc[3 * i + 2];
    const float q2 = fmaf(qx, qx, fmaf(qy, qy, qz * qz));

    if (wv == 0) pc4[i] = make_float4(qx, qy, qz, q2);

    unsigned keys[KNN];
#pragma unroll
    for (int t = 0; t < KNN; ++t) keys[t] = 0xFFFFFFFFu;

    const int jbeg = wv * (NPTS / SEGS);          // chunk start
    const float* cb = pc + 3 * (size_t)jbeg;      // wave-uniform -> s_load

    float A[3 * BATCH], B[3 * BATCH];
#pragma unroll
    for (int u = 0; u < 3 * BATCH; ++u) A[u] = cb[u];

    auto process = [&](const float* C, int jbase) {
        unsigned kb[BATCH];
#pragma unroll
        for (int q = 0; q < BATCH; ++q) {
            float dx = qx - C[3 * q + 0];
            float dy = qy - C[3 * q + 1];
            float dz = qz - C[3 * q + 2];
            float d2 = fmaf(dx, dx, fmaf(dy, dy, dz * dz));
            kb[q] = (__float_as_uint(d2) & 0xFFFFC000u)
                  | (unsigned)(jbeg + jbase + q);
        }
#pragma unroll
        for (int q = 0; q < BATCH; ++q) merge_one(keys, kb[q]);
    };

#pragma unroll 1
    for (int jo = 0; jo < RUN; jo += 2 * BATCH) {
#pragma unroll
        for (int u = 0; u < 3 * BATCH; ++u) B[u] = cb[3 * (jo + BATCH) + u];
        process(A, jo);
        if (jo + 2 * BATCH < RUN) {
#pragma unroll
            for (int u = 0; u < 3 * BATCH; ++u) A[u] = cb[3 * (jo + 2 * BATCH) + u];
        }
        process(B, jo + BATCH);
    }

    // ---- 3-round tree merge across the 8 waves ----
#pragma unroll
    for (int t = 0; t < KNN; ++t) sK[tid * 17 + t] = keys[t];
    __syncthreads();
    if (wv < 4) {
        const unsigned* p = &sK[(tid + 4 * 64) * 17];
#pragma unroll
        for (int t = 0; t < KNN; ++t) merge_one(keys, p[t]);
#pragma unroll
        for (int t = 0; t < KNN; ++t) sK[tid * 17 + t] = keys[t];
    }
    __syncthreads();
    if (wv < 2) {
        const unsigned* p = &sK[(tid + 2 * 64) * 17];
#pragma unroll
        for (int t = 0; t < KNN; ++t) merge_one(keys, p[t]);
#pragma unroll
        for (int t = 0; t < KNN; ++t) sK[tid * 17 + t] = keys[t];
    }
    __syncthreads();
    if (wv == 0) {
        const unsigned* p = &sK[(tid + 64) * 17];
#pragma unroll
        for (int t = 0; t < KNN; ++t) merge_one(keys, p[t]);
        const float d16 = __uint_as_float(keys[KNN - 1] & 0xFFFFC000u);
        // margin covers fma/truncation rounding -> provably exact filter
        taufArr[i] = fmaf(d16, 1.0002f, 1e-6f) - q2;
    }
}

// ---------------------------------------------------------------------------
// K2: main filtered scan (R9-proven, 88 us). Grid (64, NPART) x 256.
// SGPR-resident candidate batches (uniform s_load bursts) with register
// ping-pong; common path 3 fma + 1 fma + cmp; exec-masked LDS append;
// flush-tighten keeps flushes statistically never (E[accepts]=8, thr 17).
// Lists written transposed: part[i][p][16].
// ---------------------------------------------------------------------------
__global__ __launch_bounds__(256, 4) void knn_main_kernel(
    const float4* __restrict__ pc4, const float* __restrict__ taufArr,
    unsigned* __restrict__ part)
{
    __shared__ unsigned sbuf[256 * CAP];
    unsigned* buf = &sbuf[threadIdx.x * CAP];

    const int i = blockIdx.x * 256 + threadIdx.x;
    const int p = blockIdx.y;

    const float4 qv = pc4[i];
    const float qx = qv.x, qy = qv.y, qz = qv.z, q2 = qv.w;

    float tauf = taufArr[i];

    unsigned keys[KNN];
#pragma unroll
    for (int t = 0; t < KNN; ++t) keys[t] = 0xFFFFFFFFu;
    int cnt = 0;

    const int jbeg = p * PLEN;
    const float4* cb = pc4 + jbeg;

    float4 A[BATCH], B[BATCH];
#pragma unroll
    for (int q = 0; q < BATCH; ++q) A[q] = cb[q];

    auto process = [&](const float4* C, int jbase) {
#pragma unroll
        for (int q = 0; q < BATCH; ++q) {
            const float4 c = C[q];
            float dot = fmaf(c.x, qx, fmaf(c.y, qy, c.z * qz));
            float d2p = fmaf(-2.0f, dot, c.w);     // d2 - |q|^2 (monotone)
            if (d2p <= tauf) {                     // exec-masked accept
                float d2 = fmaxf(d2p + q2, 0.0f);  // clamp: self ~ -1e-7
                unsigned key = (__float_as_uint(d2) & 0xFFFFC000u)
                             | (unsigned)(jbeg + jbase + q);
                buf[cnt] = key;
                ++cnt;
            }
        }
        // headroom: enter batch with cnt <= 16 -> max idx 23
        if (cnt >= CAP - BATCH) {
#pragma unroll 1
            for (int t = 0; t < cnt; ++t) merge_one(keys, buf[t]);
            cnt = 0;
            float d16n = __uint_as_float(keys[KNN - 1] & 0xFFFFC000u);
            tauf = fminf(tauf, fmaf(d16n, 1.0002f, 1e-6f) - q2);  // NaN-safe
        }
    };

#pragma unroll 1
    for (int jo = 0; jo < PLEN; jo += 2 * BATCH) {
#pragma unroll
        for (int q = 0; q < BATCH; ++q) B[q] = cb[jo + BATCH + q];
        process(A, jo);
        if (jo + 2 * BATCH < PLEN) {
#pragma unroll
            for (int q = 0; q < BATCH; ++q) A[q] = cb[jo + 2 * BATCH + q];
        }
        process(B, jo + BATCH);
    }

#pragma unroll 1
    for (int t = 0; t < cnt; ++t) merge_one(keys, buf[t]);

    unsigned* dst = part + ((size_t)i * NPART + p) * KNN;
#pragma unroll
    for (int t = 0; t < KNN; ++t) dst[t] = keys[t];
}

// ---------------------------------------------------------------------------
// K3: merge + radius + loss + wsum + finalize (R13-proven). Grid (64,4) x 512.
// Split-merge: e==0 merges lists 0..7, e==1 merges 8..15 (ping-pong),
// halves meet in LDS, e==0 cross-merges + radius -> ids; all gather seq
// s = 2*sg + e; sg==0/e==0 also accumulates wsum.
// accum[0]=loss, accum[1]=wsum, accum[2]=ticket (zeroed by K1).
// ---------------------------------------------------------------------------
__global__ __launch_bounds__(512) void loss_kernel(
    const float* __restrict__ flow, const float* __restrict__ w,
    const unsigned* __restrict__ part, float* __restrict__ accum,
    float* __restrict__ out)
{
    __shared__ unsigned sKeys[256 * 34];   // q*34 + e*17 + t
    __shared__ float sred[8];

    const int tid = threadIdx.x;
    const int q   = tid & 255;
    const int e   = tid >> 8;          // 0..1
    const int i   = blockIdx.x * 256 + q;
    const int sg  = blockIdx.y;        // 0..3

    const uint4* lists = (const uint4*)(part + ((size_t)i * NPART + e * 8) * KNN);

    unsigned keys[KNN];
#pragma unroll
    for (int t = 0; t < KNN; ++t) keys[t] = 0xFFFFFFFFu;

    uint4 A4[4], B4[4];
#pragma unroll
    for (int u = 0; u < 4; ++u) A4[u] = lists[u];

    auto merge_list = [&](const uint4* L) {
        const unsigned* lk = (const unsigned*)L;
#pragma unroll
        for (int t = 0; t < KNN; ++t) merge_one(keys, lk[t]);
    };

#pragma unroll 1
    for (int p = 0; p < 8; p += 2) {
#pragma unroll
        for (int u = 0; u < 4; ++u) B4[u] = lists[4 * (p + 1) + u];
        merge_list(A4);
        if (p + 2 < 8) {
#pragma unroll
            for (int u = 0; u < 4; ++u) A4[u] = lists[4 * (p + 2) + u];
        }
        merge_list(B4);
    }

#pragma unroll
    for (int t = 0; t < KNN; ++t) sKeys[q * 34 + e * 17 + t] = keys[t];
    __syncthreads();

    if (e == 0) {
#pragma unroll
        for (int t = 0; t < KNN; ++t) merge_one(keys, sKeys[q * 34 + 17 + t]);
        const int id0 = (int)(keys[0] & 0x3FFFu);   // nearest (self)
#pragma unroll
        for (int t = 0; t < KNN; ++t) {
            float d2t = __uint_as_float(keys[t] & 0xFFFFC000u);
            int   j   = (int)(keys[t] & 0x3FFFu);
            sKeys[q * 34 + t] = (unsigned)((d2t > 1.0f) ? id0 : j);
        }
        if (sg == 0) {                  // weight sum exactly once
            float wi = w[i];
#pragma unroll
            for (int off = 32; off > 0; off >>= 1) wi += __shfl_down(wi, off);
            if ((tid & 63) == 0) atomicAdd(&accum[1], wi);
        }
    }
    __syncthreads();

    const int s = sg * 2 + e;
    const float* fs = flow + (size_t)s * NPTS * 3;
    const float fx = fs[3 * i + 0];
    const float fy = fs[3 * i + 1];
    const float fz = fs[3 * i + 2];

    float sum = 0.0f;
#pragma unroll
    for (int t = 0; t < KNN; ++t) {
        int j = (int)sKeys[q * 34 + t];
        float dx = fx - fs[3 * j + 0];
        float dy = fy - fs[3 * j + 1];
        float dz = fz - fs[3 * j + 2];
        float sq = fmaf(dx, dx, fmaf(dy, dy, dz * dz));
        sum += (sq > 0.0f) ? sqrtf(sq) : 0.0f;
    }

    float contrib = w[i] * sum;
#pragma unroll
    for (int off = 32; off > 0; off >>= 1) contrib += __shfl_down(contrib, off);
    if ((tid & 63) == 0) sred[tid >> 6] = contrib;
    __syncthreads();

    if (tid == 0) {
        float c = 0.0f;
#pragma unroll
        for (int t = 0; t < 8; ++t) c += sred[t];
        atomicAdd(&accum[0], c);
        __threadfence();
        unsigned ticket = atomicAdd((unsigned*)&accum[2], 1u);
        if (ticket == 64 * 4 - 1) {     // last block finalizes
            float a  = atomicAdd(&accum[0], 0.0f);   // coherent read
            float ws = atomicAdd(&accum[1], 0.0f);
            float v  = a / (float)(KNN * SEQV);
            out[0] = (ws > 0.0f) ? (v / ws) : v;
        }
    }
}

extern "C" void kernel_launch(void* const* d_in, const int* in_sizes, int n_in,
                              void* d_out, int out_size, void* d_ws, size_t ws_size,
                              hipStream_t stream)
{
    const float* pc   = (const float*)d_in[0];   // (1, N, 3)
    const float* flow = (const float*)d_in[1];   // (SEQ, N, 3)
    const float* wts  = (const float*)d_in[2];   // (N,)
    float* out = (float*)d_out;

    // layout: accum(256 B) | tauf(64 KB) | pc4(256 KB) | part(16.8 MB)
    float*    accum = (float*)d_ws;
    float*    tauf  = (float*)((char*)d_ws + 256);
    float4*   pc4   = (float4*)((char*)d_ws + 256 + NPTS * 4);
    unsigned* part  = (unsigned*)((char*)d_ws + 256 + NPTS * 4 + NPTS * 16);

    sample_tau_kernel<<<NPTS / 64, 512, 0, stream>>>(pc, pc4, tauf, accum);
    knn_main_kernel<<<dim3(NPTS / 256, NPART), 256, 0, stream>>>(pc4, tauf, part);
    loss_kernel<<<dim3(NPTS / 256, 4), 512, 0, stream>>>(flow, wts, part, accum, out);
}